// Round 3
// baseline (1514.115 us; speedup 1.0000x reference)
//
#include <hip/hip_runtime.h>
#include <math.h>

#define B_ 2
#define L_ 2048
#define DMODEL 2048
#define DINNER 4096
#define DSTATE 16
#define DCONV 4
#define DTRANK 128
#define NCHUNK 16
#define CLEN 128          // L_/NCHUNK

typedef unsigned short ushort_t;
typedef unsigned int uint_t;
typedef __attribute__((ext_vector_type(8))) short bf16x8;
typedef __attribute__((ext_vector_type(4))) float floatx4;

__device__ __forceinline__ float sigmoidf_(float x){ return 1.f/(1.f+__expf(-x)); }
__device__ __forceinline__ ushort_t f2bf(float f){
    uint_t u = __builtin_bit_cast(uint_t, f);
    return (ushort_t)((u + 0x7FFFu + ((u >> 16) & 1u)) >> 16);
}
__device__ __forceinline__ float bf2f(ushort_t h){
    return __builtin_bit_cast(float, (uint_t)h << 16);
}

#define GLD_LDS16(g, l) __builtin_amdgcn_global_load_lds( \
    (const __attribute__((address_space(1))) void*)(g),   \
    (__attribute__((address_space(3))) void*)(l), 16, 0, 0)

// ---------------------------------------------------------------------------
// bf16 MFMA GEMM: C[M,N] = A[M,K] * W[N,K]^T, 128x128 tile, BK=32, 4 waves.
// AF32: A fp32, converted during reg->LDS staging; else bf16 via async DMA.
// OUTBF: store bf16. EPI: v = softplus(v + bias[col]). NMASK: mask col < Nn.
// ---------------------------------------------------------------------------
template<int AF32, int OUTBF, int EPI, int NMASK>
__global__ __launch_bounds__(256)
void gemm_mfma(const void* __restrict__ Aptr, int lda,
               const ushort_t* __restrict__ W, int ldw,
               void* __restrict__ Cptr, int ldc, int K, int Nn,
               const float* __restrict__ bias)
{
    __shared__ ushort_t lsA[128*32];
    __shared__ ushort_t lsW[128*32];
    const int tid  = threadIdx.x;
    const int row0 = blockIdx.y * 128;
    const int col0 = blockIdx.x * 128;
    const int lane = tid & 63;
    const int wv   = tid >> 6;
    const int wm   = (wv >> 1) * 64;
    const int wn   = (wv & 1) * 64;
    const int lr   = lane & 15;
    const int lq   = lane >> 4;

    floatx4 acc[4][4];
    #pragma unroll
    for(int i=0;i<4;i++)
        #pragma unroll
        for(int j=0;j<4;j++)
            #pragma unroll
            for(int r=0;r<4;r++) acc[i][j][r] = 0.f;

    for(int k0 = 0; k0 < K; k0 += 32){
        #pragma unroll
        for(int it=0; it<2; it++){
            const int slot = it*256 + tid;
            const int row  = slot >> 2;
            const int seg  = slot & 3;
            const ushort_t* g = W + (size_t)(col0 + row)*ldw + k0 + seg*8;
            GLD_LDS16(g, &lsW[slot*8]);
        }
        if (AF32){
            const float* Af = (const float*)Aptr;
            const int row  = tid >> 1;
            const int half = (tid & 1) * 16;
            const float* s = Af + (size_t)(row0 + row)*lda + k0 + half;
            float4 v0 = *(const float4*)(s + 0);
            float4 v1 = *(const float4*)(s + 4);
            float4 v2 = *(const float4*)(s + 8);
            float4 v3 = *(const float4*)(s + 12);
            union { ushort_t u[8]; uint4 q; } p0, p1;
            p0.u[0]=f2bf(v0.x); p0.u[1]=f2bf(v0.y); p0.u[2]=f2bf(v0.z); p0.u[3]=f2bf(v0.w);
            p0.u[4]=f2bf(v1.x); p0.u[5]=f2bf(v1.y); p0.u[6]=f2bf(v1.z); p0.u[7]=f2bf(v1.w);
            p1.u[0]=f2bf(v2.x); p1.u[1]=f2bf(v2.y); p1.u[2]=f2bf(v2.z); p1.u[3]=f2bf(v2.w);
            p1.u[4]=f2bf(v3.x); p1.u[5]=f2bf(v3.y); p1.u[6]=f2bf(v3.z); p1.u[7]=f2bf(v3.w);
            *(uint4*)&lsA[row*32 + half    ] = p0.q;
            *(uint4*)&lsA[row*32 + half + 8] = p1.q;
        } else {
            #pragma unroll
            for(int it=0; it<2; it++){
                const int slot = it*256 + tid;
                const int row  = slot >> 2;
                const int seg  = slot & 3;
                const ushort_t* g = (const ushort_t*)Aptr + (size_t)(row0 + row)*lda + k0 + seg*8;
                GLD_LDS16(g, &lsA[slot*8]);
            }
        }
        __syncthreads();

        bf16x8 af[4], bw[4];
        #pragma unroll
        for(int i=0;i<4;i++){
            af[i] = *(const bf16x8*)&lsA[(wm + i*16 + lr)*32 + lq*8];
            bw[i] = *(const bf16x8*)&lsW[(wn + i*16 + lr)*32 + lq*8];
        }
        #pragma unroll
        for(int i=0;i<4;i++)
            #pragma unroll
            for(int j=0;j<4;j++)
                acc[i][j] = __builtin_amdgcn_mfma_f32_16x16x32_bf16(af[i], bw[j], acc[i][j], 0, 0, 0);
        __syncthreads();
    }

    #pragma unroll
    for(int i=0;i<4;i++){
        #pragma unroll
        for(int r=0;r<4;r++){
            const int row = row0 + wm + i*16 + lq*4 + r;
            #pragma unroll
            for(int j=0;j<4;j++){
                const int col = col0 + wn + j*16 + lr;
                if (NMASK && col >= Nn) continue;
                float v = acc[i][j][r];
                if (EPI){
                    v += bias[col];
                    v = (v > 20.f) ? v : log1pf(expf(v));
                }
                if (OUTBF) ((ushort_t*)Cptr)[(size_t)row*ldc + col] = f2bf(v);
                else       ((float*)  Cptr)[(size_t)row*ldc + col] = v;
            }
        }
    }
}

// f32 -> bf16 cast, 4 elems/thread
__global__ __launch_bounds__(256)
void cvt_bf16(const float* __restrict__ in, ushort_t* __restrict__ out, int n4)
{
    const int i = blockIdx.x*256 + threadIdx.x;
    if (i < n4){
        float4 v = *(const float4*)(in + (size_t)i*4);
        union { ushort_t u[4]; uint2 q; } p;
        p.u[0]=f2bf(v.x); p.u[1]=f2bf(v.y); p.u[2]=f2bf(v.z); p.u[3]=f2bf(v.w);
        *(uint2*)(out + (size_t)i*4) = p.q;
    }
}

// w_xproj 160x4096 f32 -> 256x4096 bf16, rows 160..255 zero
__global__ __launch_bounds__(256)
void cvt_pad256(const float* __restrict__ in, ushort_t* __restrict__ out)
{
    const int i = blockIdx.x*256 + threadIdx.x;   // 256*4096/4 = 262144 total
    const int row = i >> 10;
    const int c4  = i & 1023;
    union { ushort_t u[4]; uint2 q; } p;
    if (row < 160){
        float4 v = *(const float4*)(in + (size_t)row*4096 + c4*4);
        p.u[0]=f2bf(v.x); p.u[1]=f2bf(v.y); p.u[2]=f2bf(v.z); p.u[3]=f2bf(v.w);
    } else { p.u[0]=0; p.u[1]=0; p.u[2]=0; p.u[3]=0; }
    *(uint2*)(out + (size_t)i*4) = p.q;
}

// dt_lo: xdbl[:, 0:128] f32 (ld 160) -> bf16 [4096x128]
__global__ __launch_bounds__(256)
void cvt_dtlo(const float* __restrict__ xdbl, ushort_t* __restrict__ out)
{
    const int i = blockIdx.x*256 + threadIdx.x;   // 4096*32 = 131072 total
    const int row = i >> 5;
    const int c4  = i & 31;
    float4 v = *(const float4*)(xdbl + (size_t)row*160 + c4*4);
    union { ushort_t u[4]; uint2 q; } p;
    p.u[0]=f2bf(v.x); p.u[1]=f2bf(v.y); p.u[2]=f2bf(v.z); p.u[3]=f2bf(v.w);
    *(uint2*)(out + (size_t)i*4) = p.q;
}

// depthwise causal conv (k=4) + bias + silu -> bf16
__global__ __launch_bounds__(256)
void conv_silu_bf(const float* __restrict__ xbuf, const float* __restrict__ w,
                  const float* __restrict__ bias, ushort_t* __restrict__ xc)
{
    const int gid = blockIdx.x*256 + threadIdx.x;
    const int d = gid % DINNER;
    const int t = gid / DINNER;
    const int l = t % L_;
    float s = bias[d];
    #pragma unroll
    for(int j=0;j<DCONV;j++){
        const int ll = l - (DCONV-1) + j;
        if (ll >= 0)
            s = fmaf(xbuf[(size_t)(t-(DCONV-1)+j)*DINNER + d], w[d*DCONV+j], s);
    }
    xc[(size_t)t*DINNER + d] = f2bf(s * sigmoidf_(s));
}

// ---- chunked scan: phase 1 -- per (b,d,n,chunk) local h_end + log-decay S ----
__global__ __launch_bounds__(256)
void scan_phase1(const ushort_t* __restrict__ dt_bf,
                 const ushort_t* __restrict__ xconv,
                 const float* __restrict__ xdbl,
                 const float* __restrict__ A_log,
                 float* __restrict__ sc_h, float* __restrict__ sc_S)
{
    const int tid = threadIdx.x;
    const int g = blockIdx.x*16 + (tid>>4);       // 0..131071
    const int n = tid & 15;
    const int chunk = g & (NCHUNK-1);
    const int ch = g >> 4;                        // 0..8191 = b*DINNER+d
    const int b = ch >> 12;
    const int d = ch & (DINNER-1);

    const float negA = -expf(A_log[d*DSTATE + n]);
    float h = 0.f, S = 0.f;
    const int l0 = chunk*CLEN;
    size_t idx = ((size_t)(b*L_ + l0))*DINNER + d;
    size_t r   = ((size_t)(b*L_ + l0))*160 + DTRANK + n;
    #pragma unroll 4
    for(int s=0; s<CLEN; s++){
        const float dt = bf2f(dt_bf[idx]);
        const float xv = bf2f(xconv[idx]);
        const float Bt = xdbl[r];
        const float t = dt*negA;
        S += t;
        h = fmaf(h, __expf(t), dt*xv*Bt);
        idx += DINNER; r += 160;
    }
    sc_h[(size_t)ch*256 + n*16 + chunk] = h;
    sc_S[(size_t)ch*256 + n*16 + chunk] = S;
}

// ---- phase 2 -- serial combine over chunks; sc_h[c] becomes incoming state ----
__global__ __launch_bounds__(256)
void scan_phase2(float* __restrict__ sc_h, const float* __restrict__ sc_S)
{
    const int gid = blockIdx.x*256 + threadIdx.x;  // 0..131071 = ch*16+n
    const size_t base = (size_t)gid*16;
    float H = 0.f;
    #pragma unroll
    for(int c=0;c<NCHUNK;c++){
        const float he = sc_h[base+c];
        const float S  = sc_S[base+c];
        sc_h[base+c] = H;
        H = fmaf(__expf(S), H, he);
    }
}

// ---- phase 3 -- recompute with exact incoming state, reduce, gate, emit y ----
__global__ __launch_bounds__(256)
void scan_phase3(const ushort_t* __restrict__ dt_bf,
                 const ushort_t* __restrict__ xconv,
                 const float* __restrict__ xdbl,
                 const ushort_t* __restrict__ z_bf,
                 const float* __restrict__ A_log,
                 const float* __restrict__ Dvec,
                 const float* __restrict__ sc_h,
                 ushort_t* __restrict__ y_bf)
{
    const int tid = threadIdx.x;
    const int g = blockIdx.x*16 + (tid>>4);
    const int n = tid & 15;
    const int chunk = g & (NCHUNK-1);
    const int ch = g >> 4;
    const int b = ch >> 12;
    const int d = ch & (DINNER-1);

    const float negA = -expf(A_log[d*DSTATE + n]);
    const float Dv = Dvec[d];
    float h = sc_h[(size_t)ch*256 + n*16 + chunk];
    const int l0 = chunk*CLEN;
    const size_t base_td = ((size_t)(b*L_ + l0))*DINNER + d;
    const size_t base_r  = ((size_t)(b*L_ + l0))*160 + DTRANK;

    for(int s0=0; s0<CLEN; s0+=8){
        float dtv[8], xvv[8], Btv[8], Ctv[8], zvv[8];
        #pragma unroll
        for(int u=0;u<8;u++){
            const size_t idx = base_td + (size_t)(s0+u)*DINNER;
            dtv[u] = bf2f(dt_bf[idx]);
            xvv[u] = bf2f(xconv[idx]);
            zvv[u] = bf2f(z_bf[idx]);
            const size_t r = base_r + (size_t)(s0+u)*160;
            Btv[u] = xdbl[r + n];
            Ctv[u] = xdbl[r + DSTATE + n];
        }
        float outs[8];
        #pragma unroll
        for(int u=0;u<8;u++){
            const float t = dtv[u]*negA;
            h = fmaf(h, __expf(t), dtv[u]*xvv[u]*Btv[u]);
            float y = h * Ctv[u];
            y += __shfl_xor(y, 1);
            y += __shfl_xor(y, 2);
            y += __shfl_xor(y, 4);
            y += __shfl_xor(y, 8);
            outs[u] = fmaf(xvv[u], Dv, y) * (zvv[u] * sigmoidf_(zvv[u]));
        }
        float sel = outs[0];
        #pragma unroll
        for(int u=1;u<8;u++) if (n == u) sel = outs[u];
        if (n < 8)
            y_bf[base_td + (size_t)(s0+n)*DINNER] = f2bf(sel);
    }
}

extern "C" void kernel_launch(void* const* d_in, const int* in_sizes, int n_in,
                              void* d_out, int out_size, void* d_ws, size_t ws_size,
                              hipStream_t stream) {
    const float* hs      = (const float*)d_in[0];
    const float* w_in    = (const float*)d_in[1];
    const float* w_conv  = (const float*)d_in[2];
    const float* b_conv  = (const float*)d_in[3];
    const float* w_xproj = (const float*)d_in[4];
    const float* w_dt    = (const float*)d_in[5];
    const float* b_dt    = (const float*)d_in[6];
    const float* w_out   = (const float*)d_in[7];
    const float* A_log   = (const float*)d_in[8];
    const float* Dvec    = (const float*)d_in[9];
    float* out = (float*)d_out;

    // workspace (peak 192 MB; >=194.6 MB proven available in round 1):
    // [0,64M)   xbuf f32 (in_proj x). After conv dead -> smalls:
    //           wx_bf@0(2M) xdbl@4M(2.62M) dt_lo_bf@8M(1M) wdt_bf@10M(1M)
    //           sc_h@12M(8M) sc_S@20M(8M) wo_bf@28M(16M)
    // [64M,96M)  xconv bf16
    // [96M,128M) z_bf
    // [128M,192M) wi_bf (both halves). Dead after in_proj ->
    //           dt_bf@128M(32M) y_bf@160M(32M)
    char* base = (char*)d_ws;
    float*    xbuf   = (float*)   (base);
    ushort_t* wx_bf  = (ushort_t*)(base);
    float*    xdbl   = (float*)   (base + (4u<<20));
    ushort_t* dtlo_bf= (ushort_t*)(base + (8u<<20));
    ushort_t* wdt_bf = (ushort_t*)(base + (10u<<20));
    float*    sc_h   = (float*)   (base + (12u<<20));
    float*    sc_S   = (float*)   (base + (20u<<20));
    ushort_t* wo_bf  = (ushort_t*)(base + (28u<<20));
    ushort_t* xconv  = (ushort_t*)(base + (64u<<20));
    ushort_t* z_bf   = (ushort_t*)(base + (96u<<20));
    ushort_t* wi_bf  = (ushort_t*)(base + (128u<<20));
    ushort_t* dt_bf  = (ushort_t*)(base + (128u<<20));
    ushort_t* y_bf   = (ushort_t*)(base + (160u<<20));

    const int M = B_*L_;   // 4096
    dim3 blk(256);

    // convert full in_proj weight once
    cvt_bf16<<<dim3(2*DINNER*DMODEL/4/256), blk, 0, stream>>>(w_in, wi_bf, 2*DINNER*DMODEL/4);
    // in_proj x-half (fp32 out, feeds conv) and z-half (bf16 out)
    gemm_mfma<1,0,0,0><<<dim3(DINNER/128, M/128), blk, 0, stream>>>(
        hs, DMODEL, wi_bf, DMODEL, xbuf, DINNER, DMODEL, DINNER, nullptr);
    gemm_mfma<1,1,0,0><<<dim3(DINNER/128, M/128), blk, 0, stream>>>(
        hs, DMODEL, wi_bf + (size_t)DINNER*DMODEL, DMODEL, z_bf, DINNER, DMODEL, DINNER, nullptr);

    // conv + silu -> bf16 (xbuf region becomes free after this)
    conv_silu_bf<<<dim3((size_t)M*DINNER/256), blk, 0, stream>>>(xbuf, w_conv, b_conv, xconv);

    // x_proj: bf16 MFMA, N=160 (W padded to 256 rows)
    cvt_pad256<<<dim3(256*4096/4/256), blk, 0, stream>>>(w_xproj, wx_bf);
    gemm_mfma<0,0,0,1><<<dim3(2, M/128), blk, 0, stream>>>(
        xconv, DINNER, wx_bf, DINNER, xdbl, 160, DINNER, 160, nullptr);

    // dt_proj: bf16 MFMA K=128, fused bias+softplus -> dt_bf
    cvt_dtlo<<<dim3(M*32/256), blk, 0, stream>>>(xdbl, dtlo_bf);
    cvt_bf16<<<dim3(DINNER*DTRANK/4/256), blk, 0, stream>>>(w_dt, wdt_bf, DINNER*DTRANK/4);
    gemm_mfma<0,1,1,0><<<dim3(DINNER/128, M/128), blk, 0, stream>>>(
        dtlo_bf, DTRANK, wdt_bf, DTRANK, dt_bf, DINNER, DTRANK, DINNER, b_dt);

    // chunked selective scan
    scan_phase1<<<dim3(B_*DINNER*NCHUNK/16), blk, 0, stream>>>(
        dt_bf, xconv, xdbl, A_log, sc_h, sc_S);
    scan_phase2<<<dim3(B_*DINNER*DSTATE/256), blk, 0, stream>>>(sc_h, sc_S);
    scan_phase3<<<dim3(B_*DINNER*NCHUNK/16), blk, 0, stream>>>(
        dt_bf, xconv, xdbl, z_bf, A_log, Dvec, sc_h, y_bf);

    // out_proj
    cvt_bf16<<<dim3(DMODEL*DINNER/4/256), blk, 0, stream>>>(w_out, wo_bf, DMODEL*DINNER/4);
    gemm_mfma<0,0,0,0><<<dim3(DMODEL/128, M/128), blk, 0, stream>>>(
        y_bf, DINNER, wo_bf, DINNER, out, DMODEL, DINNER, DMODEL, nullptr);
}

// Round 4
// 825.252 us; speedup vs baseline: 1.8347x; 1.8347x over previous
//
#include <hip/hip_runtime.h>
#include <math.h>

#define B_ 2
#define L_ 2048
#define DMODEL 2048
#define DINNER 4096
#define DSTATE 16
#define DCONV 4
#define DTRANK 128
#define NCHUNK 32
#define CLEN 64           // L_/NCHUNK

typedef unsigned short ushort_t;
typedef unsigned int uint_t;
typedef __attribute__((ext_vector_type(8))) short bf16x8;
typedef __attribute__((ext_vector_type(4))) float floatx4;

__device__ __forceinline__ float sigmoidf_(float x){ return 1.f/(1.f+__expf(-x)); }
__device__ __forceinline__ ushort_t f2bf(float f){
    uint_t u = __builtin_bit_cast(uint_t, f);
    return (ushort_t)((u + 0x7FFFu + ((u >> 16) & 1u)) >> 16);
}
__device__ __forceinline__ float bf2f(ushort_t h){
    return __builtin_bit_cast(float, (uint_t)h << 16);
}
__device__ __forceinline__ float fast_exp2(float x){
#if __has_builtin(__builtin_amdgcn_exp2f)
    return __builtin_amdgcn_exp2f(x);
#else
    return exp2f(x);
#endif
}
#define LOG2E 1.44269504088896f

#define GLD_LDS16(g, l) __builtin_amdgcn_global_load_lds( \
    (const __attribute__((address_space(1))) void*)(g),   \
    (__attribute__((address_space(3))) void*)(l), 16, 0, 0)

// ---------------------------------------------------------------------------
// bf16 MFMA GEMM: C[M,N] = A[M,K] * W[N,K]^T, 128x128 tile, BK=32, 4 waves.
// OUTBF: store bf16. EPI: v = softplus(v + bias[col]). NMASK: mask col < Nn.
// ---------------------------------------------------------------------------
template<int OUTBF, int EPI, int NMASK>
__global__ __launch_bounds__(256)
void gemm_mfma(const ushort_t* __restrict__ Aptr, int lda,
               const ushort_t* __restrict__ W, int ldw,
               void* __restrict__ Cptr, int ldc, int K, int Nn,
               const float* __restrict__ bias)
{
    __shared__ ushort_t lsA[128*32];
    __shared__ ushort_t lsW[128*32];
    const int tid  = threadIdx.x;
    const int row0 = blockIdx.y * 128;
    const int col0 = blockIdx.x * 128;
    const int lane = tid & 63;
    const int wv   = tid >> 6;
    const int wm   = (wv >> 1) * 64;
    const int wn   = (wv & 1) * 64;
    const int lr   = lane & 15;
    const int lq   = lane >> 4;

    floatx4 acc[4][4];
    #pragma unroll
    for(int i=0;i<4;i++)
        #pragma unroll
        for(int j=0;j<4;j++)
            #pragma unroll
            for(int r=0;r<4;r++) acc[i][j][r] = 0.f;

    for(int k0 = 0; k0 < K; k0 += 32){
        #pragma unroll
        for(int it=0; it<2; it++){
            const int slot = it*256 + tid;
            const int row  = slot >> 2;
            const int seg  = slot & 3;
            const ushort_t* g = W + (size_t)(col0 + row)*ldw + k0 + seg*8;
            GLD_LDS16(g, &lsW[slot*8]);
        }
        #pragma unroll
        for(int it=0; it<2; it++){
            const int slot = it*256 + tid;
            const int row  = slot >> 2;
            const int seg  = slot & 3;
            const ushort_t* g = Aptr + (size_t)(row0 + row)*lda + k0 + seg*8;
            GLD_LDS16(g, &lsA[slot*8]);
        }
        __syncthreads();

        bf16x8 af[4], bw[4];
        #pragma unroll
        for(int i=0;i<4;i++){
            af[i] = *(const bf16x8*)&lsA[(wm + i*16 + lr)*32 + lq*8];
            bw[i] = *(const bf16x8*)&lsW[(wn + i*16 + lr)*32 + lq*8];
        }
        #pragma unroll
        for(int i=0;i<4;i++)
            #pragma unroll
            for(int j=0;j<4;j++)
                acc[i][j] = __builtin_amdgcn_mfma_f32_16x16x32_bf16(af[i], bw[j], acc[i][j], 0, 0, 0);
        __syncthreads();
    }

    #pragma unroll
    for(int i=0;i<4;i++){
        #pragma unroll
        for(int r=0;r<4;r++){
            const int row = row0 + wm + i*16 + lq*4 + r;
            #pragma unroll
            for(int j=0;j<4;j++){
                const int col = col0 + wn + j*16 + lr;
                if (NMASK && col >= Nn) continue;
                float v = acc[i][j][r];
                if (EPI){
                    v += bias[col];
                    v = (v > 20.f) ? v : log1pf(expf(v));
                }
                if (OUTBF) ((ushort_t*)Cptr)[(size_t)row*ldc + col] = f2bf(v);
                else       ((float*)  Cptr)[(size_t)row*ldc + col] = v;
            }
        }
    }
}

// f32 -> bf16 cast, 4 elems/thread
__global__ __launch_bounds__(256)
void cvt_bf16(const float* __restrict__ in, ushort_t* __restrict__ out, int n4)
{
    const int i = blockIdx.x*256 + threadIdx.x;
    if (i < n4){
        float4 v = *(const float4*)(in + (size_t)i*4);
        union { ushort_t u[4]; uint2 q; } p;
        p.u[0]=f2bf(v.x); p.u[1]=f2bf(v.y); p.u[2]=f2bf(v.z); p.u[3]=f2bf(v.w);
        *(uint2*)(out + (size_t)i*4) = p.q;
    }
}

// w_xproj 160x4096 f32 -> 256x4096 bf16, rows 160..255 zero
__global__ __launch_bounds__(256)
void cvt_pad256(const float* __restrict__ in, ushort_t* __restrict__ out)
{
    const int i = blockIdx.x*256 + threadIdx.x;
    const int row = i >> 10;
    const int c4  = i & 1023;
    union { ushort_t u[4]; uint2 q; } p;
    if (row < 160){
        float4 v = *(const float4*)(in + (size_t)row*4096 + c4*4);
        p.u[0]=f2bf(v.x); p.u[1]=f2bf(v.y); p.u[2]=f2bf(v.z); p.u[3]=f2bf(v.w);
    } else { p.u[0]=0; p.u[1]=0; p.u[2]=0; p.u[3]=0; }
    *(uint2*)(out + (size_t)i*4) = p.q;
}

// dt_lo: xdbl[:, 0:128] f32 (ld 160) -> bf16 [4096x128]
__global__ __launch_bounds__(256)
void cvt_dtlo(const float* __restrict__ xdbl, ushort_t* __restrict__ out)
{
    const int i = blockIdx.x*256 + threadIdx.x;
    const int row = i >> 5;
    const int c4  = i & 31;
    float4 v = *(const float4*)(xdbl + (size_t)row*160 + c4*4);
    union { ushort_t u[4]; uint2 q; } p;
    p.u[0]=f2bf(v.x); p.u[1]=f2bf(v.y); p.u[2]=f2bf(v.z); p.u[3]=f2bf(v.w);
    *(uint2*)(out + (size_t)i*4) = p.q;
}

// depthwise causal conv (k=4) + bias + silu, bf16 in/out
__global__ __launch_bounds__(256)
void conv_silu_bf(const ushort_t* __restrict__ xb, const float* __restrict__ w,
                  const float* __restrict__ bias, ushort_t* __restrict__ xc)
{
    const int gid = blockIdx.x*256 + threadIdx.x;
    const int d = gid % DINNER;
    const int t = gid / DINNER;
    const int l = t % L_;
    float s = bias[d];
    #pragma unroll
    for(int j=0;j<DCONV;j++){
        const int ll = l - (DCONV-1) + j;
        if (ll >= 0)
            s = fmaf(bf2f(xb[(size_t)(t-(DCONV-1)+j)*DINNER + d]), w[d*DCONV+j], s);
    }
    xc[(size_t)t*DINNER + d] = f2bf(s * sigmoidf_(s));
}

// ---- chunked scan, one thread per channel d, 16 states in registers ----
// phase 1: local scan from h=0; emit h_end[n] and log2-decay S[n]
__global__ __launch_bounds__(256)
void scan_phase1(const ushort_t* __restrict__ dt_bf,
                 const ushort_t* __restrict__ xconv,
                 const float* __restrict__ xdbl,
                 const float* __restrict__ A_log,
                 float* __restrict__ sc_h, float* __restrict__ sc_S)
{
    const int tid = threadIdx.x;
    const int d = blockIdx.x*256 + tid;
    const int chunk = blockIdx.y;
    const int b = blockIdx.z;
    const int l0 = chunk*CLEN;

    __shared__ float Bs[CLEN][DSTATE];
    for(int i=tid; i<CLEN*DSTATE; i+=256){
        const int row = i >> 4, n = i & 15;
        Bs[row][n] = xdbl[(size_t)(b*L_ + l0 + row)*160 + DTRANK + n];
    }
    float negA[DSTATE];
    #pragma unroll
    for(int n=0;n<DSTATE;n++) negA[n] = -expf(A_log[d*DSTATE + n]) * LOG2E;
    __syncthreads();

    float h[DSTATE], S[DSTATE];
    #pragma unroll
    for(int n=0;n<DSTATE;n++){ h[n]=0.f; S[n]=0.f; }

    size_t idx = (size_t)(b*L_ + l0)*DINNER + d;
    float dt_c = bf2f(dt_bf[idx]);
    float xv_c = bf2f(xconv[idx]);
    for(int l=0;l<CLEN;l++){
        float dt_n = 0.f, xv_n = 0.f;
        if (l+1 < CLEN){
            dt_n = bf2f(dt_bf[idx + DINNER]);
            xv_n = bf2f(xconv[idx + DINNER]);
        }
        const float dx = dt_c * xv_c;
        #pragma unroll
        for(int n=0;n<DSTATE;n++){
            const float t = dt_c * negA[n];
            S[n] += t;
            h[n] = fmaf(h[n], fast_exp2(t), dx*Bs[l][n]);
        }
        dt_c = dt_n; xv_c = xv_n;
        idx += DINNER;
    }
    const size_t o = (size_t)(b*NCHUNK + chunk)*DSTATE*DINNER + d;
    #pragma unroll
    for(int n=0;n<DSTATE;n++){
        sc_h[o + (size_t)n*DINNER] = h[n];
        sc_S[o + (size_t)n*DINNER] = S[n];
    }
}

// phase 2: serial combine over chunks; sc_h[c] becomes incoming state
__global__ __launch_bounds__(256)
void scan_phase2(float* __restrict__ sc_h, const float* __restrict__ sc_S)
{
    const int gid = blockIdx.x*256 + threadIdx.x;   // (b*DSTATE+n)*DINNER+d
    const int b = gid / (DSTATE*DINNER);
    const int rem = gid - b*DSTATE*DINNER;
    const size_t base = (size_t)b*NCHUNK*DSTATE*DINNER + rem;
    float H = 0.f;
    #pragma unroll
    for(int c=0;c<NCHUNK;c++){
        const size_t idx = base + (size_t)c*DSTATE*DINNER;
        const float he = sc_h[idx];
        const float S  = sc_S[idx];
        sc_h[idx] = H;
        H = fmaf(fast_exp2(S), H, he);
    }
}

// phase 3: rescan from exact incoming state, reduce over n, gate, emit y
__global__ __launch_bounds__(256)
void scan_phase3(const ushort_t* __restrict__ dt_bf,
                 const ushort_t* __restrict__ xconv,
                 const float* __restrict__ xdbl,
                 const ushort_t* __restrict__ z_bf,
                 const float* __restrict__ A_log,
                 const float* __restrict__ Dvec,
                 const float* __restrict__ sc_h,
                 ushort_t* __restrict__ y_bf)
{
    const int tid = threadIdx.x;
    const int d = blockIdx.x*256 + tid;
    const int chunk = blockIdx.y;
    const int b = blockIdx.z;
    const int l0 = chunk*CLEN;

    __shared__ float BCs[CLEN][2*DSTATE];
    for(int i=tid; i<CLEN*2*DSTATE; i+=256){
        const int row = i >> 5, c = i & 31;
        BCs[row][c] = xdbl[(size_t)(b*L_ + l0 + row)*160 + DTRANK + c];
    }
    float negA[DSTATE];
    #pragma unroll
    for(int n=0;n<DSTATE;n++) negA[n] = -expf(A_log[d*DSTATE + n]) * LOG2E;
    const float Dv = Dvec[d];
    float h[DSTATE];
    const size_t o = (size_t)(b*NCHUNK + chunk)*DSTATE*DINNER + d;
    #pragma unroll
    for(int n=0;n<DSTATE;n++) h[n] = sc_h[o + (size_t)n*DINNER];
    __syncthreads();

    size_t idx = (size_t)(b*L_ + l0)*DINNER + d;
    float dt_c = bf2f(dt_bf[idx]);
    float xv_c = bf2f(xconv[idx]);
    float zv_c = bf2f(z_bf[idx]);
    for(int l=0;l<CLEN;l++){
        float dt_n = 0.f, xv_n = 0.f, zv_n = 0.f;
        if (l+1 < CLEN){
            dt_n = bf2f(dt_bf[idx + DINNER]);
            xv_n = bf2f(xconv[idx + DINNER]);
            zv_n = bf2f(z_bf[idx + DINNER]);
        }
        const float dx = dt_c * xv_c;
        float y = 0.f;
        #pragma unroll
        for(int n=0;n<DSTATE;n++){
            const float t = dt_c * negA[n];
            h[n] = fmaf(h[n], fast_exp2(t), dx*BCs[l][n]);
            y = fmaf(h[n], BCs[l][DSTATE+n], y);
        }
        const float g = zv_c * sigmoidf_(zv_c);
        y_bf[idx] = f2bf(fmaf(xv_c, Dv, y) * g);
        dt_c = dt_n; xv_c = xv_n; zv_c = zv_n;
        idx += DINNER;
    }
}

extern "C" void kernel_launch(void* const* d_in, const int* in_sizes, int n_in,
                              void* d_out, int out_size, void* d_ws, size_t ws_size,
                              hipStream_t stream) {
    const float* hs      = (const float*)d_in[0];
    const float* w_in    = (const float*)d_in[1];
    const float* w_conv  = (const float*)d_in[2];
    const float* b_conv  = (const float*)d_in[3];
    const float* w_xproj = (const float*)d_in[4];
    const float* w_dt    = (const float*)d_in[5];
    const float* b_dt    = (const float*)d_in[6];
    const float* w_out   = (const float*)d_in[7];
    const float* A_log   = (const float*)d_in[8];
    const float* Dvec    = (const float*)d_in[9];
    float* out = (float*)d_out;

    // workspace layout (peak 184 MiB; 192 MiB proven available round 3):
    // [0,32M)    x_bf (in_proj x, bf16)  -> after conv: dt_bf
    // [32M,64M)  xconv bf16
    // [64M,96M)  z_bf bf16
    // [96M,128M) wi_bf (in_proj w, bf16) -> after in_proj: sc_h@96M, sc_S@112M
    // [128M,144M) hs_bf                  -> after in_proj: wo_bf
    // [144M,176M) y_bf
    // [176M,...) xdbl(2.62M) wx_bf(2M) dtlo_bf(1M) wdt_bf(1M)
    char* base = (char*)d_ws;
    ushort_t* x_bf   = (ushort_t*)(base);
    ushort_t* dt_bf  = (ushort_t*)(base);
    ushort_t* xconv  = (ushort_t*)(base + (32u<<20));
    ushort_t* z_bf   = (ushort_t*)(base + (64u<<20));
    ushort_t* wi_bf  = (ushort_t*)(base + (96u<<20));
    float*    sc_h   = (float*)   (base + (96u<<20));
    float*    sc_S   = (float*)   (base + (112u<<20));
    ushort_t* hs_bf  = (ushort_t*)(base + (128u<<20));
    ushort_t* wo_bf  = (ushort_t*)(base + (128u<<20));
    ushort_t* y_bf   = (ushort_t*)(base + (144u<<20));
    float*    xdbl   = (float*)   (base + (176u<<20));
    ushort_t* wx_bf  = (ushort_t*)(base + (179u<<20));
    ushort_t* dtlo_bf= (ushort_t*)(base + (181u<<20));
    ushort_t* wdt_bf = (ushort_t*)(base + (182u<<20));

    const int M = B_*L_;   // 4096
    dim3 blk(256);

    // convert activations + in_proj weights to bf16
    cvt_bf16<<<dim3(M*DMODEL/4/256), blk, 0, stream>>>(hs, hs_bf, M*DMODEL/4);
    cvt_bf16<<<dim3(2*DINNER*DMODEL/4/256), blk, 0, stream>>>(w_in, wi_bf, 2*DINNER*DMODEL/4);

    // in_proj x-half and z-half (both bf16 out)
    gemm_mfma<1,0,0><<<dim3(DINNER/128, M/128), blk, 0, stream>>>(
        hs_bf, DMODEL, wi_bf, DMODEL, x_bf, DINNER, DMODEL, DINNER, nullptr);
    gemm_mfma<1,0,0><<<dim3(DINNER/128, M/128), blk, 0, stream>>>(
        hs_bf, DMODEL, wi_bf + (size_t)DINNER*DMODEL, DMODEL, z_bf, DINNER, DMODEL, DINNER, nullptr);

    // conv + silu -> xconv bf16 (x_bf region becomes free after this)
    conv_silu_bf<<<dim3((size_t)M*DINNER/256), blk, 0, stream>>>(x_bf, w_conv, b_conv, xconv);

    // x_proj: N=160 (W padded to 256 rows)
    cvt_pad256<<<dim3(256*4096/4/256), blk, 0, stream>>>(w_xproj, wx_bf);
    gemm_mfma<0,0,1><<<dim3(2, M/128), blk, 0, stream>>>(
        xconv, DINNER, wx_bf, DINNER, xdbl, 160, DINNER, 160, nullptr);

    // dt_proj + bias + softplus -> dt_bf (overwrites dead x_bf region)
    cvt_dtlo<<<dim3(M*32/256), blk, 0, stream>>>(xdbl, dtlo_bf);
    cvt_bf16<<<dim3(DINNER*DTRANK/4/256), blk, 0, stream>>>(w_dt, wdt_bf, DINNER*DTRANK/4);
    gemm_mfma<1,1,0><<<dim3(DINNER/128, M/128), blk, 0, stream>>>(
        dtlo_bf, DTRANK, wdt_bf, DTRANK, dt_bf, DINNER, DTRANK, DINNER, b_dt);

    // chunked selective scan (thread-per-channel, coalesced)
    dim3 sgrid(DINNER/256, NCHUNK, B_);
    scan_phase1<<<sgrid, blk, 0, stream>>>(dt_bf, xconv, xdbl, A_log, sc_h, sc_S);
    scan_phase2<<<dim3(B_*DSTATE*DINNER/256), blk, 0, stream>>>(sc_h, sc_S);
    scan_phase3<<<sgrid, blk, 0, stream>>>(dt_bf, xconv, xdbl, z_bf, A_log, Dvec, sc_h, y_bf);

    // out_proj (wo_bf overwrites dead hs_bf region)
    cvt_bf16<<<dim3(DMODEL*DINNER/4/256), blk, 0, stream>>>(w_out, wo_bf, DMODEL*DINNER/4);
    gemm_mfma<0,0,0><<<dim3(DMODEL/128, M/128), blk, 0, stream>>>(
        y_bf, DINNER, wo_bf, DINNER, out, DMODEL, DINNER, DMODEL, nullptr);
}

// Round 5
// 802.641 us; speedup vs baseline: 1.8864x; 1.0282x over previous
//
#include <hip/hip_runtime.h>
#include <math.h>

#define B_ 2
#define L_ 2048
#define DMODEL 2048
#define DINNER 4096
#define DSTATE 16
#define DCONV 4
#define DTRANK 128
#define NCHUNK 32
#define CLEN 64           // L_/NCHUNK

typedef unsigned short ushort_t;
typedef unsigned int uint_t;
typedef __attribute__((ext_vector_type(8))) short bf16x8;
typedef __attribute__((ext_vector_type(4))) float floatx4;

__device__ __forceinline__ float sigmoidf_(float x){ return 1.f/(1.f+__expf(-x)); }
__device__ __forceinline__ ushort_t f2bf(float f){
    uint_t u = __builtin_bit_cast(uint_t, f);
    return (ushort_t)((u + 0x7FFFu + ((u >> 16) & 1u)) >> 16);
}
__device__ __forceinline__ float bf2f(ushort_t h){
    return __builtin_bit_cast(float, (uint_t)h << 16);
}
__device__ __forceinline__ float fast_exp2(float x){
#if __has_builtin(__builtin_amdgcn_exp2f)
    return __builtin_amdgcn_exp2f(x);
#else
    return exp2f(x);
#endif
}
#define LOG2E 1.44269504088896f

#define GLD_LDS16(g, l) __builtin_amdgcn_global_load_lds( \
    (const __attribute__((address_space(1))) void*)(g),   \
    (__attribute__((address_space(3))) void*)(l), 16, 0, 0)

// ---------------------------------------------------------------------------
// bf16 MFMA GEMM: C[M,N] = A[M,K] * W[N,K]^T, 128x128 tile, BK=32, 4 waves.
// LDS layout XOR-swizzled: segment seg of row r stored at column seg^((r>>1)&3)
// -> ds_read_b128 by 16 lanes spreads over all 32 banks (2-way = free).
// OUTBF: store bf16. EPI: softplus(v+bias[col]). NMASK: mask col<Nn.
// SPLIT: cols < NS go to Cptr, cols >= NS go to C2 (col-NS); both ldc=NS.
// ---------------------------------------------------------------------------
template<int OUTBF, int EPI, int NMASK, int SPLIT>
__global__ __launch_bounds__(256)
void gemm_mfma(const ushort_t* __restrict__ Aptr, int lda,
               const ushort_t* __restrict__ W, int ldw,
               void* __restrict__ Cptr, void* __restrict__ C2,
               int ldc, int K, int Nn,
               const float* __restrict__ bias)
{
    __shared__ ushort_t lsA[128*32];
    __shared__ ushort_t lsW[128*32];
    const int tid  = threadIdx.x;
    const int row0 = blockIdx.y * 128;
    const int col0 = blockIdx.x * 128;
    const int lane = tid & 63;
    const int wv   = tid >> 6;
    const int wm   = (wv >> 1) * 64;
    const int wn   = (wv & 1) * 64;
    const int lr   = lane & 15;
    const int lq   = lane >> 4;
    const int swc  = ((lq ^ (lr >> 1)) & 3) * 8;   // swizzled read column (ushorts)

    floatx4 acc[4][4];
    #pragma unroll
    for(int i=0;i<4;i++)
        #pragma unroll
        for(int j=0;j<4;j++)
            #pragma unroll
            for(int r=0;r<4;r++) acc[i][j][r] = 0.f;

    for(int k0 = 0; k0 < K; k0 += 32){
        #pragma unroll
        for(int it=0; it<2; it++){
            const int slot = it*256 + tid;
            const int row  = slot >> 2;
            const int seg  = (slot ^ (row >> 1)) & 3;   // inverse swizzle on source
            const ushort_t* gw = W    + (size_t)(col0 + row)*ldw + k0 + seg*8;
            const ushort_t* ga = Aptr + (size_t)(row0 + row)*lda + k0 + seg*8;
            GLD_LDS16(gw, &lsW[slot*8]);
            GLD_LDS16(ga, &lsA[slot*8]);
        }
        __syncthreads();

        bf16x8 af[4], bw[4];
        #pragma unroll
        for(int i=0;i<4;i++){
            af[i] = *(const bf16x8*)&lsA[(wm + i*16 + lr)*32 + swc];
            bw[i] = *(const bf16x8*)&lsW[(wn + i*16 + lr)*32 + swc];
        }
        #pragma unroll
        for(int i=0;i<4;i++)
            #pragma unroll
            for(int j=0;j<4;j++)
                acc[i][j] = __builtin_amdgcn_mfma_f32_16x16x32_bf16(af[i], bw[j], acc[i][j], 0, 0, 0);
        __syncthreads();
    }

    void* dst = Cptr;
    int cbase = col0;
    if (SPLIT && col0 >= ldc){ dst = C2; cbase = col0 - ldc; }

    #pragma unroll
    for(int i=0;i<4;i++){
        #pragma unroll
        for(int r=0;r<4;r++){
            const int row = row0 + wm + i*16 + lq*4 + r;
            #pragma unroll
            for(int j=0;j<4;j++){
                const int col = cbase + wn + j*16 + lr;
                if (NMASK && col >= Nn) continue;
                float v = acc[i][j][r];
                if (EPI){
                    v += bias[col];
                    v = (v > 20.f) ? v : log1pf(expf(v));
                }
                if (OUTBF) ((ushort_t*)dst)[(size_t)row*ldc + col] = f2bf(v);
                else       ((float*)  dst)[(size_t)row*ldc + col] = v;
            }
        }
    }
}

// f32 -> bf16 cast, 4 elems/thread
__global__ __launch_bounds__(256)
void cvt_bf16(const float* __restrict__ in, ushort_t* __restrict__ out, int n4)
{
    const int i = blockIdx.x*256 + threadIdx.x;
    if (i < n4){
        float4 v = *(const float4*)(in + (size_t)i*4);
        union { ushort_t u[4]; uint2 q; } p;
        p.u[0]=f2bf(v.x); p.u[1]=f2bf(v.y); p.u[2]=f2bf(v.z); p.u[3]=f2bf(v.w);
        *(uint2*)(out + (size_t)i*4) = p.q;
    }
}

// w_xproj 160x4096 f32 -> 256x4096 bf16, rows 160..255 zero
__global__ __launch_bounds__(256)
void cvt_pad256(const float* __restrict__ in, ushort_t* __restrict__ out)
{
    const int i = blockIdx.x*256 + threadIdx.x;
    const int row = i >> 10;
    const int c4  = i & 1023;
    union { ushort_t u[4]; uint2 q; } p;
    if (row < 160){
        float4 v = *(const float4*)(in + (size_t)row*4096 + c4*4);
        p.u[0]=f2bf(v.x); p.u[1]=f2bf(v.y); p.u[2]=f2bf(v.z); p.u[3]=f2bf(v.w);
    } else { p.u[0]=0; p.u[1]=0; p.u[2]=0; p.u[3]=0; }
    *(uint2*)(out + (size_t)i*4) = p.q;
}

// dt_lo: xdbl[:, 0:128] f32 (ld 160) -> bf16 [4096x128]
__global__ __launch_bounds__(256)
void cvt_dtlo(const float* __restrict__ xdbl, ushort_t* __restrict__ out)
{
    const int i = blockIdx.x*256 + threadIdx.x;
    const int row = i >> 5;
    const int c4  = i & 31;
    float4 v = *(const float4*)(xdbl + (size_t)row*160 + c4*4);
    union { ushort_t u[4]; uint2 q; } p;
    p.u[0]=f2bf(v.x); p.u[1]=f2bf(v.y); p.u[2]=f2bf(v.z); p.u[3]=f2bf(v.w);
    *(uint2*)(out + (size_t)i*4) = p.q;
}

// depthwise causal conv (k=4) + bias + silu, bf16 in/out
__global__ __launch_bounds__(256)
void conv_silu_bf(const ushort_t* __restrict__ xb, const float* __restrict__ w,
                  const float* __restrict__ bias, ushort_t* __restrict__ xc)
{
    const int gid = blockIdx.x*256 + threadIdx.x;
    const int d = gid & (DINNER-1);
    const int t = gid >> 12;
    const int l = t & (L_-1);
    float s = bias[d];
    #pragma unroll
    for(int j=0;j<DCONV;j++){
        const int ll = l - (DCONV-1) + j;
        if (ll >= 0)
            s = fmaf(bf2f(xb[(size_t)(t-(DCONV-1)+j)*DINNER + d]), w[d*DCONV+j], s);
    }
    xc[(size_t)t*DINNER + d] = f2bf(s * sigmoidf_(s));
}

// ---- chunked scan, one thread per channel d, 16 states in registers ----
__global__ __launch_bounds__(256)
void scan_phase1(const ushort_t* __restrict__ dt_bf,
                 const ushort_t* __restrict__ xconv,
                 const float* __restrict__ xdbl,
                 const float* __restrict__ A_log,
                 float* __restrict__ sc_h, float* __restrict__ sc_S)
{
    const int tid = threadIdx.x;
    const int d = blockIdx.x*256 + tid;
    const int chunk = blockIdx.y;
    const int b = blockIdx.z;
    const int l0 = chunk*CLEN;

    __shared__ float Bs[CLEN][DSTATE];
    for(int i=tid; i<CLEN*DSTATE; i+=256){
        const int row = i >> 4, n = i & 15;
        Bs[row][n] = xdbl[(size_t)(b*L_ + l0 + row)*160 + DTRANK + n];
    }
    float negA[DSTATE];
    #pragma unroll
    for(int n=0;n<DSTATE;n++) negA[n] = -expf(A_log[d*DSTATE + n]) * LOG2E;
    __syncthreads();

    float h[DSTATE], S[DSTATE];
    #pragma unroll
    for(int n=0;n<DSTATE;n++){ h[n]=0.f; S[n]=0.f; }

    size_t idx = (size_t)(b*L_ + l0)*DINNER + d;
    float dt_c = bf2f(dt_bf[idx]);
    float xv_c = bf2f(xconv[idx]);
    for(int l=0;l<CLEN;l++){
        float dt_n = 0.f, xv_n = 0.f;
        if (l+1 < CLEN){
            dt_n = bf2f(dt_bf[idx + DINNER]);
            xv_n = bf2f(xconv[idx + DINNER]);
        }
        const float dx = dt_c * xv_c;
        #pragma unroll
        for(int n=0;n<DSTATE;n++){
            const float t = dt_c * negA[n];
            S[n] += t;
            h[n] = fmaf(h[n], fast_exp2(t), dx*Bs[l][n]);
        }
        dt_c = dt_n; xv_c = xv_n;
        idx += DINNER;
    }
    const size_t o = (size_t)(b*NCHUNK + chunk)*DSTATE*DINNER + d;
    #pragma unroll
    for(int n=0;n<DSTATE;n++){
        sc_h[o + (size_t)n*DINNER] = h[n];
        sc_S[o + (size_t)n*DINNER] = S[n];
    }
}

__global__ __launch_bounds__(256)
void scan_phase2(float* __restrict__ sc_h, const float* __restrict__ sc_S)
{
    const int gid = blockIdx.x*256 + threadIdx.x;
    const int b = gid / (DSTATE*DINNER);
    const int rem = gid - b*DSTATE*DINNER;
    const size_t base = (size_t)b*NCHUNK*DSTATE*DINNER + rem;
    float H = 0.f;
    #pragma unroll
    for(int c=0;c<NCHUNK;c++){
        const size_t idx = base + (size_t)c*DSTATE*DINNER;
        const float he = sc_h[idx];
        const float S  = sc_S[idx];
        sc_h[idx] = H;
        H = fmaf(fast_exp2(S), H, he);
    }
}

__global__ __launch_bounds__(256)
void scan_phase3(const ushort_t* __restrict__ dt_bf,
                 const ushort_t* __restrict__ xconv,
                 const float* __restrict__ xdbl,
                 const ushort_t* __restrict__ z_bf,
                 const float* __restrict__ A_log,
                 const float* __restrict__ Dvec,
                 const float* __restrict__ sc_h,
                 ushort_t* __restrict__ y_bf)
{
    const int tid = threadIdx.x;
    const int d = blockIdx.x*256 + tid;
    const int chunk = blockIdx.y;
    const int b = blockIdx.z;
    const int l0 = chunk*CLEN;

    __shared__ float BCs[CLEN][2*DSTATE];
    for(int i=tid; i<CLEN*2*DSTATE; i+=256){
        const int row = i >> 5, c = i & 31;
        BCs[row][c] = xdbl[(size_t)(b*L_ + l0 + row)*160 + DTRANK + c];
    }
    float negA[DSTATE];
    #pragma unroll
    for(int n=0;n<DSTATE;n++) negA[n] = -expf(A_log[d*DSTATE + n]) * LOG2E;
    const float Dv = Dvec[d];
    float h[DSTATE];
    const size_t o = (size_t)(b*NCHUNK + chunk)*DSTATE*DINNER + d;
    #pragma unroll
    for(int n=0;n<DSTATE;n++) h[n] = sc_h[o + (size_t)n*DINNER];
    __syncthreads();

    size_t idx = (size_t)(b*L_ + l0)*DINNER + d;
    float dt_c = bf2f(dt_bf[idx]);
    float xv_c = bf2f(xconv[idx]);
    float zv_c = bf2f(z_bf[idx]);
    for(int l=0;l<CLEN;l++){
        float dt_n = 0.f, xv_n = 0.f, zv_n = 0.f;
        if (l+1 < CLEN){
            dt_n = bf2f(dt_bf[idx + DINNER]);
            xv_n = bf2f(xconv[idx + DINNER]);
            zv_n = bf2f(z_bf[idx + DINNER]);
        }
        const float dx = dt_c * xv_c;
        float y = 0.f;
        #pragma unroll
        for(int n=0;n<DSTATE;n++){
            const float t = dt_c * negA[n];
            h[n] = fmaf(h[n], fast_exp2(t), dx*BCs[l][n]);
            y = fmaf(h[n], BCs[l][DSTATE+n], y);
        }
        const float g = zv_c * sigmoidf_(zv_c);
        y_bf[idx] = f2bf(fmaf(xv_c, Dv, y) * g);
        dt_c = dt_n; xv_c = xv_n; zv_c = zv_n;
        idx += DINNER;
    }
}

extern "C" void kernel_launch(void* const* d_in, const int* in_sizes, int n_in,
                              void* d_out, int out_size, void* d_ws, size_t ws_size,
                              hipStream_t stream) {
    const float* hs      = (const float*)d_in[0];
    const float* w_in    = (const float*)d_in[1];
    const float* w_conv  = (const float*)d_in[2];
    const float* b_conv  = (const float*)d_in[3];
    const float* w_xproj = (const float*)d_in[4];
    const float* w_dt    = (const float*)d_in[5];
    const float* b_dt    = (const float*)d_in[6];
    const float* w_out   = (const float*)d_in[7];
    const float* A_log   = (const float*)d_in[8];
    const float* Dvec    = (const float*)d_in[9];
    float* out = (float*)d_out;

    // workspace layout (peak 176 MiB; 192 MiB proven in rounds 3-4):
    // [0,32M)    x_bf -> after conv: xdbl@0, wx_bf@4M, dtlo@6M, wdt@7M, sc_h@8M(16M)
    // [32M,64M)  z_bf               (live to phase3)
    // [64M,96M)  xconv              (live to phase3)
    // [96M,128M) wi_bf -> after in_proj: dt_bf
    // [128M,144M) hs_bf -> after in_proj: sc_S -> after phase2: wo_bf
    // [144M,176M) y_bf
    char* base = (char*)d_ws;
    ushort_t* x_bf   = (ushort_t*)(base);
    float*    xdbl   = (float*)   (base);
    ushort_t* wx_bf  = (ushort_t*)(base + (4u<<20));
    ushort_t* dtlo_bf= (ushort_t*)(base + (6u<<20));
    ushort_t* wdt_bf = (ushort_t*)(base + (7u<<20));
    float*    sc_h   = (float*)   (base + (8u<<20));
    ushort_t* z_bf   = (ushort_t*)(base + (32u<<20));
    ushort_t* xconv  = (ushort_t*)(base + (64u<<20));
    ushort_t* wi_bf  = (ushort_t*)(base + (96u<<20));
    ushort_t* dt_bf  = (ushort_t*)(base + (96u<<20));
    ushort_t* hs_bf  = (ushort_t*)(base + (128u<<20));
    float*    sc_S   = (float*)   (base + (128u<<20));
    ushort_t* wo_bf  = (ushort_t*)(base + (128u<<20));
    ushort_t* y_bf   = (ushort_t*)(base + (144u<<20));

    const int M = B_*L_;   // 4096
    dim3 blk(256);

    // convert activations + in_proj weights to bf16
    cvt_bf16<<<dim3(M*DMODEL/4/256), blk, 0, stream>>>(hs, hs_bf, M*DMODEL/4);
    cvt_bf16<<<dim3(2*DINNER*DMODEL/4/256), blk, 0, stream>>>(w_in, wi_bf, 2*DINNER*DMODEL/4);

    // fused in_proj: N=8192, split-store x half / z half
    gemm_mfma<1,0,0,1><<<dim3(2*DINNER/128, M/128), blk, 0, stream>>>(
        hs_bf, DMODEL, wi_bf, DMODEL, x_bf, z_bf, DINNER, DMODEL, DINNER, nullptr);

    // conv + silu -> xconv bf16 (x_bf region becomes free after this)
    conv_silu_bf<<<dim3((size_t)M*DINNER/256), blk, 0, stream>>>(x_bf, w_conv, b_conv, xconv);

    // x_proj: N=160 (W padded to 256 rows)
    cvt_pad256<<<dim3(256*4096/4/256), blk, 0, stream>>>(w_xproj, wx_bf);
    gemm_mfma<0,0,1,0><<<dim3(2, M/128), blk, 0, stream>>>(
        xconv, DINNER, wx_bf, DINNER, xdbl, nullptr, 160, DINNER, 160, nullptr);

    // dt_proj + bias + softplus -> dt_bf (overwrites dead wi_bf region)
    cvt_dtlo<<<dim3(M*32/256), blk, 0, stream>>>(xdbl, dtlo_bf);
    cvt_bf16<<<dim3(DINNER*DTRANK/4/256), blk, 0, stream>>>(w_dt, wdt_bf, DINNER*DTRANK/4);
    gemm_mfma<1,1,0,0><<<dim3(DINNER/128, M/128), blk, 0, stream>>>(
        dtlo_bf, DTRANK, wdt_bf, DTRANK, dt_bf, nullptr, DINNER, DTRANK, DINNER, b_dt);

    // chunked selective scan (thread-per-channel, coalesced)
    dim3 sgrid(DINNER/256, NCHUNK, B_);
    scan_phase1<<<sgrid, blk, 0, stream>>>(dt_bf, xconv, xdbl, A_log, sc_h, sc_S);
    scan_phase2<<<dim3(B_*DSTATE*DINNER/256), blk, 0, stream>>>(sc_h, sc_S);

    // w_out conversion (sc_S dead after phase2; reuse its region)
    cvt_bf16<<<dim3(DMODEL*DINNER/4/256), blk, 0, stream>>>(w_out, wo_bf, DMODEL*DINNER/4);

    scan_phase3<<<sgrid, blk, 0, stream>>>(dt_bf, xconv, xdbl, z_bf, A_log, Dvec, sc_h, y_bf);

    // out_proj
    gemm_mfma<0,0,0,0><<<dim3(DMODEL/128, M/128), blk, 0, stream>>>(
        y_bf, DINNER, wo_bf, DINNER, out, nullptr, DMODEL, DINNER, DMODEL, nullptr);
}

// Round 6
// 685.395 us; speedup vs baseline: 2.2091x; 1.1711x over previous
//
#include <hip/hip_runtime.h>
#include <math.h>

#define B_ 2
#define L_ 2048
#define DMODEL 2048
#define DINNER 4096
#define DSTATE 16
#define DCONV 4
#define DTRANK 128
#define NCHUNK 32
#define CLEN 64           // L_/NCHUNK
#define MROWS 4096        // B_*L_

typedef unsigned short ushort_t;
typedef unsigned int uint_t;
typedef __attribute__((ext_vector_type(8))) short bf16x8;
typedef __attribute__((ext_vector_type(4))) float floatx4;

__device__ __forceinline__ float sigmoidf_(float x){ return 1.f/(1.f+__expf(-x)); }
__device__ __forceinline__ ushort_t f2bf(float f){
    uint_t u = __builtin_bit_cast(uint_t, f);
    return (ushort_t)((u + 0x7FFFu + ((u >> 16) & 1u)) >> 16);
}
__device__ __forceinline__ float bf2f(ushort_t h){
    return __builtin_bit_cast(float, (uint_t)h << 16);
}
__device__ __forceinline__ float fast_exp2(float x){
#if __has_builtin(__builtin_amdgcn_exp2f)
    return __builtin_amdgcn_exp2f(x);
#else
    return exp2f(x);
#endif
}
#define LOG2E 1.44269504088896f

#define GLD_LDS16(g, l) __builtin_amdgcn_global_load_lds( \
    (const __attribute__((address_space(1))) void*)(g),   \
    (__attribute__((address_space(3))) void*)(l), 16, 0, 0)

// ---------------------------------------------------------------------------
// bf16 MFMA GEMM: C[M,N] = A[M,K]*W[N,K]^T. 128x128 tile, BK=64, 4 waves.
// grid = (row-tiles, col-tiles, ksplits): consecutive blocks share a W tile.
// LDS rows are 64 ushorts (128 B); 8 x 16B segments XOR-swizzled p = s^(row&7)
// so 16-lane ds_read_b128 groups span all 32 banks (2-way = free).
// OUTBF: store bf16. EPI: softplus(v+bias[col]).
// SPLIT: cols >= ldc go to C2 (col-ldc). KSPLIT: f32 partials per blockIdx.z.
// Klen = K per z-slice; K total = gridDim.z * Klen.
// ---------------------------------------------------------------------------
template<int OUTBF, int EPI, int SPLIT, int KSPLIT>
__global__ __launch_bounds__(256)
void gemm_mfma(const ushort_t* __restrict__ Aptr, int lda,
               const ushort_t* __restrict__ W, int ldw,
               void* __restrict__ Cptr, void* __restrict__ C2,
               int ldc, int Klen,
               const float* __restrict__ bias)
{
    __shared__ ushort_t lsA[128*64];
    __shared__ ushort_t lsW[128*64];
    const int tid  = threadIdx.x;
    const int row0 = blockIdx.x * 128;
    const int col0 = blockIdx.y * 128;
    const int koff = KSPLIT ? blockIdx.z * Klen : 0;
    const int lane = tid & 63;
    const int wv   = tid >> 6;
    const int wm   = (wv >> 1) * 64;
    const int wn   = (wv & 1) * 64;
    const int lr   = lane & 15;
    const int lq   = lane >> 4;

    floatx4 acc[4][4];
    #pragma unroll
    for(int i=0;i<4;i++)
        #pragma unroll
        for(int j=0;j<4;j++)
            #pragma unroll
            for(int r=0;r<4;r++) acc[i][j][r] = 0.f;

    for(int k0 = koff; k0 < koff + Klen; k0 += 64){
        // stage 128x64 A and W tiles: 4 x 16B per thread per tensor
        #pragma unroll
        for(int it=0; it<4; it++){
            const int slot = it*256 + tid;
            const int row  = slot >> 3;
            const int p    = slot & 7;
            const int s    = p ^ (row & 7);          // inverse swizzle on source
            const ushort_t* gw = W    + (size_t)(col0 + row)*ldw + k0 + s*8;
            const ushort_t* ga = Aptr + (size_t)(row0 + row)*lda + k0 + s*8;
            GLD_LDS16(gw, &lsW[slot*8]);
            GLD_LDS16(ga, &lsA[slot*8]);
        }
        __syncthreads();

        #pragma unroll
        for(int kk=0; kk<2; kk++){
            bf16x8 af[4], bw[4];
            #pragma unroll
            for(int i=0;i<4;i++){
                const int ra = wm + i*16 + lr;
                const int rb = wn + i*16 + lr;
                af[i] = *(const bf16x8*)&lsA[ra*64 + (((kk*4+lq) ^ (ra&7))*8)];
                bw[i] = *(const bf16x8*)&lsW[rb*64 + (((kk*4+lq) ^ (rb&7))*8)];
            }
            #pragma unroll
            for(int i=0;i<4;i++)
                #pragma unroll
                for(int j=0;j<4;j++)
                    acc[i][j] = __builtin_amdgcn_mfma_f32_16x16x32_bf16(af[i], bw[j], acc[i][j], 0, 0, 0);
        }
        __syncthreads();
    }

    void* dst = Cptr;
    int cbase = col0;
    if (SPLIT && col0 >= ldc){ dst = C2; cbase = col0 - ldc; }
    const size_t zoff = KSPLIT ? (size_t)blockIdx.z * MROWS * ldc : 0;

    #pragma unroll
    for(int i=0;i<4;i++){
        #pragma unroll
        for(int r=0;r<4;r++){
            const int row = row0 + wm + i*16 + lq*4 + r;
            #pragma unroll
            for(int j=0;j<4;j++){
                const int col = cbase + wn + j*16 + lr;
                float v = acc[i][j][r];
                if (EPI){
                    v += bias[col];
                    v = (v > 20.f) ? v : log1pf(expf(v));
                }
                if (OUTBF) ((ushort_t*)dst)[(size_t)row*ldc + col] = f2bf(v);
                else       ((float*)  dst)[zoff + (size_t)row*ldc + col] = v;
            }
        }
    }
}

// f32 -> bf16 cast, 4 elems/thread
__global__ __launch_bounds__(256)
void cvt_bf16(const float* __restrict__ in, ushort_t* __restrict__ out, int n4)
{
    const int i = blockIdx.x*256 + threadIdx.x;
    if (i < n4){
        float4 v = *(const float4*)(in + (size_t)i*4);
        union { ushort_t u[4]; uint2 q; } p;
        p.u[0]=f2bf(v.x); p.u[1]=f2bf(v.y); p.u[2]=f2bf(v.z); p.u[3]=f2bf(v.w);
        *(uint2*)(out + (size_t)i*4) = p.q;
    }
}

// w_xproj 160x4096 f32 -> 256x4096 bf16, rows 160..255 zero
__global__ __launch_bounds__(256)
void cvt_pad256(const float* __restrict__ in, ushort_t* __restrict__ out)
{
    const int i = blockIdx.x*256 + threadIdx.x;
    const int row = i >> 10;
    const int c4  = i & 1023;
    union { ushort_t u[4]; uint2 q; } p;
    if (row < 160){
        float4 v = *(const float4*)(in + (size_t)row*4096 + c4*4);
        p.u[0]=f2bf(v.x); p.u[1]=f2bf(v.y); p.u[2]=f2bf(v.z); p.u[3]=f2bf(v.w);
    } else { p.u[0]=0; p.u[1]=0; p.u[2]=0; p.u[3]=0; }
    *(uint2*)(out + (size_t)i*4) = p.q;
}

// reduce split-K partials P[8][4096][256] -> xdbl f32 (ld 160) + dtlo bf16 (ld 128)
__global__ __launch_bounds__(256)
void reduce_xproj(const float* __restrict__ P, float* __restrict__ xdbl,
                  ushort_t* __restrict__ dtlo)
{
    const int row = blockIdx.x;
    const int col = threadIdx.x;
    float s = 0.f;
    #pragma unroll
    for(int z=0; z<8; z++)
        s += P[(size_t)z*MROWS*256 + (size_t)row*256 + col];
    if (col < 160) xdbl[(size_t)row*160 + col] = s;
    if (col < DTRANK) dtlo[(size_t)row*DTRANK + col] = f2bf(s);
}

// depthwise causal conv (k=4) + bias + silu, bf16 in/out
__global__ __launch_bounds__(256)
void conv_silu_bf(const ushort_t* __restrict__ xb, const float* __restrict__ w,
                  const float* __restrict__ bias, ushort_t* __restrict__ xc)
{
    const int gid = blockIdx.x*256 + threadIdx.x;
    const int d = gid & (DINNER-1);
    const int t = gid >> 12;
    const int l = t & (L_-1);
    float s = bias[d];
    #pragma unroll
    for(int j=0;j<DCONV;j++){
        const int ll = l - (DCONV-1) + j;
        if (ll >= 0)
            s = fmaf(bf2f(xb[(size_t)(t-(DCONV-1)+j)*DINNER + d]), w[d*DCONV+j], s);
    }
    xc[(size_t)t*DINNER + d] = f2bf(s * sigmoidf_(s));
}

// ---- chunked scan, one thread per channel d, 16 states in registers ----
__global__ __launch_bounds__(256)
void scan_phase1(const ushort_t* __restrict__ dt_bf,
                 const ushort_t* __restrict__ xconv,
                 const float* __restrict__ xdbl,
                 const float* __restrict__ A_log,
                 float* __restrict__ sc_h, float* __restrict__ sc_S)
{
    const int tid = threadIdx.x;
    const int d = blockIdx.x*256 + tid;
    const int chunk = blockIdx.y;
    const int b = blockIdx.z;
    const int l0 = chunk*CLEN;

    __shared__ float Bs[CLEN][DSTATE];
    for(int i=tid; i<CLEN*DSTATE; i+=256){
        const int row = i >> 4, n = i & 15;
        Bs[row][n] = xdbl[(size_t)(b*L_ + l0 + row)*160 + DTRANK + n];
    }
    float negA[DSTATE];
    #pragma unroll
    for(int n=0;n<DSTATE;n++) negA[n] = -expf(A_log[d*DSTATE + n]) * LOG2E;
    __syncthreads();

    float h[DSTATE], S[DSTATE];
    #pragma unroll
    for(int n=0;n<DSTATE;n++){ h[n]=0.f; S[n]=0.f; }

    size_t idx = (size_t)(b*L_ + l0)*DINNER + d;
    float dt_c = bf2f(dt_bf[idx]);
    float xv_c = bf2f(xconv[idx]);
    for(int l=0;l<CLEN;l++){
        float dt_n = 0.f, xv_n = 0.f;
        if (l+1 < CLEN){
            dt_n = bf2f(dt_bf[idx + DINNER]);
            xv_n = bf2f(xconv[idx + DINNER]);
        }
        const float dx = dt_c * xv_c;
        #pragma unroll
        for(int n=0;n<DSTATE;n++){
            const float t = dt_c * negA[n];
            S[n] += t;
            h[n] = fmaf(h[n], fast_exp2(t), dx*Bs[l][n]);
        }
        dt_c = dt_n; xv_c = xv_n;
        idx += DINNER;
    }
    const size_t o = (size_t)(b*NCHUNK + chunk)*DSTATE*DINNER + d;
    #pragma unroll
    for(int n=0;n<DSTATE;n++){
        sc_h[o + (size_t)n*DINNER] = h[n];
        sc_S[o + (size_t)n*DINNER] = S[n];
    }
}

__global__ __launch_bounds__(256)
void scan_phase2(float* __restrict__ sc_h, const float* __restrict__ sc_S)
{
    const int gid = blockIdx.x*256 + threadIdx.x;
    const int b = gid / (DSTATE*DINNER);
    const int rem = gid - b*DSTATE*DINNER;
    const size_t base = (size_t)b*NCHUNK*DSTATE*DINNER + rem;
    float H = 0.f;
    #pragma unroll
    for(int c=0;c<NCHUNK;c++){
        const size_t idx = base + (size_t)c*DSTATE*DINNER;
        const float he = sc_h[idx];
        const float S  = sc_S[idx];
        sc_h[idx] = H;
        H = fmaf(fast_exp2(S), H, he);
    }
}

__global__ __launch_bounds__(256)
void scan_phase3(const ushort_t* __restrict__ dt_bf,
                 const ushort_t* __restrict__ xconv,
                 const float* __restrict__ xdbl,
                 const ushort_t* __restrict__ z_bf,
                 const float* __restrict__ A_log,
                 const float* __restrict__ Dvec,
                 const float* __restrict__ sc_h,
                 ushort_t* __restrict__ y_bf)
{
    const int tid = threadIdx.x;
    const int d = blockIdx.x*256 + tid;
    const int chunk = blockIdx.y;
    const int b = blockIdx.z;
    const int l0 = chunk*CLEN;

    __shared__ float BCs[CLEN][2*DSTATE];
    for(int i=tid; i<CLEN*2*DSTATE; i+=256){
        const int row = i >> 5, c = i & 31;
        BCs[row][c] = xdbl[(size_t)(b*L_ + l0 + row)*160 + DTRANK + c];
    }
    float negA[DSTATE];
    #pragma unroll
    for(int n=0;n<DSTATE;n++) negA[n] = -expf(A_log[d*DSTATE + n]) * LOG2E;
    const float Dv = Dvec[d];
    float h[DSTATE];
    const size_t o = (size_t)(b*NCHUNK + chunk)*DSTATE*DINNER + d;
    #pragma unroll
    for(int n=0;n<DSTATE;n++) h[n] = sc_h[o + (size_t)n*DINNER];
    __syncthreads();

    size_t idx = (size_t)(b*L_ + l0)*DINNER + d;
    float dt_c = bf2f(dt_bf[idx]);
    float xv_c = bf2f(xconv[idx]);
    float zv_c = bf2f(z_bf[idx]);
    for(int l=0;l<CLEN;l++){
        float dt_n = 0.f, xv_n = 0.f, zv_n = 0.f;
        if (l+1 < CLEN){
            dt_n = bf2f(dt_bf[idx + DINNER]);
            xv_n = bf2f(xconv[idx + DINNER]);
            zv_n = bf2f(z_bf[idx + DINNER]);
        }
        const float dx = dt_c * xv_c;
        float y = 0.f;
        #pragma unroll
        for(int n=0;n<DSTATE;n++){
            const float t = dt_c * negA[n];
            h[n] = fmaf(h[n], fast_exp2(t), dx*BCs[l][n]);
            y = fmaf(h[n], BCs[l][DSTATE+n], y);
        }
        const float g = zv_c * sigmoidf_(zv_c);
        y_bf[idx] = f2bf(fmaf(xv_c, Dv, y) * g);
        dt_c = dt_n; xv_c = xv_n; zv_c = zv_n;
        idx += DINNER;
    }
}

extern "C" void kernel_launch(void* const* d_in, const int* in_sizes, int n_in,
                              void* d_out, int out_size, void* d_ws, size_t ws_size,
                              hipStream_t stream) {
    const float* hs      = (const float*)d_in[0];
    const float* w_in    = (const float*)d_in[1];
    const float* w_conv  = (const float*)d_in[2];
    const float* b_conv  = (const float*)d_in[3];
    const float* w_xproj = (const float*)d_in[4];
    const float* w_dt    = (const float*)d_in[5];
    const float* b_dt    = (const float*)d_in[6];
    const float* w_out   = (const float*)d_in[7];
    const float* A_log   = (const float*)d_in[8];
    const float* Dvec    = (const float*)d_in[9];
    float* out = (float*)d_out;

    // workspace layout (peak 176 MiB):
    // [0,32M)    x_bf -> after conv: xdbl@0, wx_bf@4M, dtlo@6M, wdt@7M, sc_h@8M(16M)
    // [32M,64M)  z_bf               (live to phase3)
    // [64M,96M)  xconv              (live to phase3)
    // [96M,128M) wi_bf -> after in_proj: dt_bf
    // [128M,144M) hs_bf -> after in_proj: sc_S -> after phase2: wo_bf
    // [144M,176M) y_bf  (also x_proj split-K partials, dead before phase3)
    char* base = (char*)d_ws;
    ushort_t* x_bf   = (ushort_t*)(base);
    float*    xdbl   = (float*)   (base);
    ushort_t* wx_bf  = (ushort_t*)(base + (4u<<20));
    ushort_t* dtlo_bf= (ushort_t*)(base + (6u<<20));
    ushort_t* wdt_bf = (ushort_t*)(base + (7u<<20));
    float*    sc_h   = (float*)   (base + (8u<<20));
    ushort_t* z_bf   = (ushort_t*)(base + (32u<<20));
    ushort_t* xconv  = (ushort_t*)(base + (64u<<20));
    ushort_t* wi_bf  = (ushort_t*)(base + (96u<<20));
    ushort_t* dt_bf  = (ushort_t*)(base + (96u<<20));
    ushort_t* hs_bf  = (ushort_t*)(base + (128u<<20));
    float*    sc_S   = (float*)   (base + (128u<<20));
    ushort_t* wo_bf  = (ushort_t*)(base + (128u<<20));
    float*    xp_par = (float*)   (base + (144u<<20));  // 8*4096*256*4 = 32 MiB
    ushort_t* y_bf   = (ushort_t*)(base + (144u<<20));

    dim3 blk(256);

    // convert activations + in_proj weights to bf16
    cvt_bf16<<<dim3(MROWS*DMODEL/4/256), blk, 0, stream>>>(hs, hs_bf, MROWS*DMODEL/4);
    cvt_bf16<<<dim3(2*DINNER*DMODEL/4/256), blk, 0, stream>>>(w_in, wi_bf, 2*DINNER*DMODEL/4);

    // fused in_proj: N=8192, split-store x half / z half
    gemm_mfma<1,0,1,0><<<dim3(MROWS/128, 2*DINNER/128), blk, 0, stream>>>(
        hs_bf, DMODEL, wi_bf, DMODEL, x_bf, z_bf, DINNER, DMODEL, nullptr);

    // conv + silu -> xconv bf16 (x_bf region becomes free after this)
    conv_silu_bf<<<dim3((size_t)MROWS*DINNER/256), blk, 0, stream>>>(x_bf, w_conv, b_conv, xconv);

    // x_proj: split-K x 8 into f32 partials, then reduce (+fused dtlo cvt)
    cvt_pad256<<<dim3(256*4096/4/256), blk, 0, stream>>>(w_xproj, wx_bf);
    gemm_mfma<0,0,0,1><<<dim3(MROWS/128, 2, 8), blk, 0, stream>>>(
        xconv, DINNER, wx_bf, DINNER, xp_par, nullptr, 256, DINNER/8, nullptr);
    reduce_xproj<<<dim3(MROWS), blk, 0, stream>>>(xp_par, xdbl, dtlo_bf);

    // dt_proj + bias + softplus -> dt_bf (overwrites dead wi_bf region)
    cvt_bf16<<<dim3(DINNER*DTRANK/4/256), blk, 0, stream>>>(w_dt, wdt_bf, DINNER*DTRANK/4);
    gemm_mfma<1,1,0,0><<<dim3(MROWS/128, DINNER/128), blk, 0, stream>>>(
        dtlo_bf, DTRANK, wdt_bf, DTRANK, dt_bf, nullptr, DINNER, DTRANK, b_dt);

    // chunked selective scan (thread-per-channel, coalesced)
    dim3 sgrid(DINNER/256, NCHUNK, B_);
    scan_phase1<<<sgrid, blk, 0, stream>>>(dt_bf, xconv, xdbl, A_log, sc_h, sc_S);
    scan_phase2<<<dim3(B_*DSTATE*DINNER/256), blk, 0, stream>>>(sc_h, sc_S);

    // w_out conversion (sc_S dead after phase2; reuse its region)
    cvt_bf16<<<dim3(DMODEL*DINNER/4/256), blk, 0, stream>>>(w_out, wo_bf, DMODEL*DINNER/4);

    scan_phase3<<<sgrid, blk, 0, stream>>>(dt_bf, xconv, xdbl, z_bf, A_log, Dvec, sc_h, y_bf);

    // out_proj
    gemm_mfma<0,0,0,0><<<dim3(MROWS/128, DMODEL/128), blk, 0, stream>>>(
        y_bf, DINNER, wo_bf, DINNER, out, nullptr, DMODEL, DINNER, nullptr);
}